// Round 5
// baseline (874.649 us; speedup 1.0000x reference)
//
#include <hip/hip_runtime.h>
#include <hip/hip_bf16.h>
#include <math.h>

// Problem constants
#define BB 2
#define CC 1024
#define HH 64
#define WW 64
#define HWH (HH*WW)          // 4096
#define TT (BB*HWH)          // 8192 tokens
#define EE 8
#define FFN 1024
#define HCAP 17408           // sum_e ceil(cnt_e/128)*128 <= 16384 + 8*127
#define MAXTILES 136         // sum_e ceil(cnt_e/128) <= 128 + 7 (pad to 136)

typedef __bf16 bf16x8 __attribute__((ext_vector_type(8)));
typedef __bf16 bf16x4 __attribute__((ext_vector_type(4)));
typedef float  f32x4  __attribute__((ext_vector_type(4)));

// async global->LDS, 16B per lane. LDS dest = wave-uniform base + lane*16.
__device__ __forceinline__ void gl_lds16(const __bf16* g, __bf16* l) {
    __builtin_amdgcn_global_load_lds(
        (const __attribute__((address_space(1))) void*)g,
        (__attribute__((address_space(3))) void*)l, 16, 0, 0);
}

__device__ __forceinline__ void barrier_raw() {
    asm volatile("" ::: "memory");
    __builtin_amdgcn_s_barrier();
    asm volatile("" ::: "memory");
}
__device__ __forceinline__ void memfence() { asm volatile("" ::: "memory"); }

// ---------------------------------------------------------------------------
// k_prep: one launch doing (a) w1/w2/w3 fp32->bf16, (b) hs transpose -> X bf16,
// (c) router partial logits (16-way K-split).  All memory-bound, overlapped.
// ---------------------------------------------------------------------------
#define CVB 12288
#define XPB 8192
#define RTB 512
__global__ __launch_bounds__(256) void k_prep(
    const float* __restrict__ hs, const float* __restrict__ gate_w,
    const float* __restrict__ w1, const float* __restrict__ w2,
    const float* __restrict__ w3,
    __bf16* __restrict__ w1b, __bf16* __restrict__ w2b,
    __bf16* __restrict__ w3b, __bf16* __restrict__ X,
    float* __restrict__ logP) {
    __shared__ float sm[2112];
    const int bid = blockIdx.x;
    const int tid = threadIdx.x;

    if (bid < CVB) {
        const float* s; __bf16* d; int lb = bid;
        if (lb < 4096)      { s = w1; d = w1b; }
        else if (lb < 8192) { s = w2; d = w2b; lb -= 4096; }
        else                { s = w3; d = w3b; lb -= 8192; }
        const size_t i = (size_t)lb * 2048 + (size_t)tid * 8;
        const f32x4 v0 = *(const f32x4*)&s[i];
        const f32x4 v1 = *(const f32x4*)&s[i + 4];
        bf16x8 o;
#pragma unroll
        for (int j = 0; j < 4; ++j) { o[j] = (__bf16)v0[j]; o[4 + j] = (__bf16)v1[j]; }
        *(bf16x8*)&d[i] = o;
    } else if (bid < CVB + XPB) {
        const int lb  = bid - CVB;
        const int hw0 = (lb & 127) * 32;
        const int c0  = ((lb >> 7) & 31) * 32;
        const int b   = lb >> 12;
        float (*tile)[33] = (float(*)[33])sm;
        const int tx = tid & 31, ty = tid >> 5;
        const float* src = hs + ((size_t)b * CC + c0) * HWH + hw0;
#pragma unroll
        for (int i = 0; i < 4; ++i)
            tile[ty + i * 8][tx] = src[(size_t)(ty + i * 8) * HWH + tx];
        __syncthreads();
        __bf16* dst = X + ((size_t)b * HWH + hw0) * CC + c0;
#pragma unroll
        for (int i = 0; i < 4; ++i) {
            const int hwl = ty + i * 8;
            dst[(size_t)hwl * CC + tx] = (__bf16)tile[tx][hwl];
        }
    } else {
        const int lb  = bid - (CVB + XPB);
        const int q   = lb & 3;
        const int t64 = lb >> 2;
        float* g = sm;
        for (int i = tid; i < 2048; i += 256)
            g[i] = gate_w[(size_t)(i >> 8) * CC + q * 256 + (i & 255)];
        __syncthreads();
        const int q2 = tid >> 6, tl = tid & 63;
        const int t  = t64 * 64 + tl;
        const int b  = t >> 12, hw = t & 4095;
        const float* xp = hs + (size_t)b * CC * HWH + hw;
        float l[EE];
#pragma unroll
        for (int e = 0; e < EE; ++e) l[e] = 0.0f;
        const int cbase = q * 256 + q2 * 64;
        for (int c2 = 0; c2 < 64; ++c2) {
            const float xv = xp[(size_t)(cbase + c2) * HWH];
#pragma unroll
            for (int e = 0; e < EE; ++e) l[e] += xv * g[e * 256 + q2 * 64 + c2];
        }
        float* dst = logP + ((size_t)(q * 4 + q2) * TT + t) * 8;
        f32x4 a, c;
#pragma unroll
        for (int e = 0; e < 4; ++e) { a[e] = l[e]; c[e] = l[4 + e]; }
        *(f32x4*)dst = a;
        *(f32x4*)&dst[4] = c;
    }
}

// ---------------------------------------------------------------------------
// k_top2: reduce 16 partials, top-2, renormalize, block-aggregated atomics.
// Writes combine weight per packed row (posW) so gemm2 can fold it in.
// ---------------------------------------------------------------------------
__global__ __launch_bounds__(256) void k_top2(const float* __restrict__ logP,
                                              int* __restrict__ cnt,
                                              int* __restrict__ idxl,
                                              int* __restrict__ tokE,
                                              int* __restrict__ tokP,
                                              float* __restrict__ posW) {
    __shared__ int lcnt[EE], lbase[EE];
    const int tid = threadIdx.x;
    const int t   = blockIdx.x * 256 + tid;
    if (tid < EE) lcnt[tid] = 0;
    __syncthreads();

    float l[EE];
#pragma unroll
    for (int e = 0; e < EE; ++e) l[e] = 0.0f;
#pragma unroll
    for (int pq = 0; pq < 16; ++pq) {
        const float* src = logP + ((size_t)pq * TT + t) * 8;
        const f32x4 a = *(const f32x4*)src;
        const f32x4 c = *(const f32x4*)&src[4];
#pragma unroll
        for (int e = 0; e < 4; ++e) { l[e] += a[e]; l[4 + e] += c[e]; }
    }

    int e1 = 0; float v1 = l[0];
#pragma unroll
    for (int e = 1; e < EE; ++e) { if (l[e] > v1) { v1 = l[e]; e1 = e; } }
    int e2 = -1; float v2 = -1e30f;
#pragma unroll
    for (int e = 0; e < EE; ++e) { if (e != e1 && l[e] > v2) { v2 = l[e]; e2 = e; } }

    const float p2 = __expf(v2 - v1);
    const float rs = 1.0f / (1.0f + p2);

    const int m1 = atomicAdd(&lcnt[e1], 1);
    const int m2 = atomicAdd(&lcnt[e2], 1);
    __syncthreads();
    if (tid < EE) lbase[tid] = atomicAdd(&cnt[tid], lcnt[tid]);
    __syncthreads();
    const int p1pos = lbase[e1] + m1;
    const int p2pos = lbase[e2] + m2;

    idxl[e1 * TT + p1pos] = t;
    idxl[e2 * TT + p2pos] = t;
    posW[e1 * TT + p1pos] = rs;
    posW[e2 * TT + p2pos] = p2 * rs;
    tokE[t] = e1 | (e2 << 8);
    tokP[2 * t]     = p1pos;
    tokP[2 * t + 1] = p2pos;
}

// ---------------------------------------------------------------------------
// k_offsets: padded prefix offsets + dense (expert, m-tile) map.
// ---------------------------------------------------------------------------
__global__ void k_offsets(const int* __restrict__ cnt, int* __restrict__ off,
                          int* __restrict__ tileE, int* __restrict__ tileM,
                          int* __restrict__ nT) {
    if (threadIdx.x == 0) {
        int a = 0, n = 0;
        for (int e = 0; e < EE; ++e) {
            off[e] = a;
            const int mt = (cnt[e] + 127) >> 7;
            for (int m = 0; m < mt; ++m) { tileE[n] = e; tileM[n] = m * 128; ++n; }
            a += mt * 128;
        }
        nT[0] = n;
    }
}

// ---------------------------------------------------------------------------
// GEMM1: H = gelu(X@W1^T)*(X@W3^T).  A in registers (direct global loads of
// gathered rows), B1/B3 double-buffered LDS via global_load_lds, ONE barrier
// per K-iter, no draining waits.  grid (FFN/128, MAXTILES).
// ---------------------------------------------------------------------------
__global__ __launch_bounds__(256, 3)
void k_gemm1(const __bf16* __restrict__ X, const __bf16* __restrict__ w1b,
             const __bf16* __restrict__ w3b, const int* __restrict__ cnt,
             const int* __restrict__ off, const int* __restrict__ idxl,
             const int* __restrict__ tileE, const int* __restrict__ tileM,
             const int* __restrict__ nT, __bf16* __restrict__ H) {
    if ((int)blockIdx.y >= nT[0]) return;
    const int e     = tileE[blockIdx.y];
    const int mt128 = tileM[blockIdx.y];
    const int cntE  = cnt[e];
    const int goff  = off[e];
    const int n0    = blockIdx.x * 128;
    const __bf16* W1 = w1b + (size_t)e * FFN * CC;
    const __bf16* W3 = w3b + (size_t)e * FFN * CC;

    __shared__ __bf16 sB1[2][128 * 32];   // 8 KB per buffer
    __shared__ __bf16 sB3[2][128 * 32];

    const int tid  = threadIdx.x;
    const int lane = tid & 63;
    const int wave = tid >> 6;
    const int wm   = (wave & 1) * 64;
    const int wn   = (wave >> 1) * 64;
    const int l15  = lane & 15;
    const int lq   = lane >> 4;
    const int rl   = lane >> 2;
    const int cpos = lane & 3;
    // XOR swizzle on k-chunks (proven conflict-free in R4)
    const int c8s = (cpos ^ ((rl >> 1) & 3)) * 8;
    const int cq  = (lq ^ ((l15 >> 1) & 3)) * 8;

    // A: 4 gathered row pointers per lane (direct-to-register loads)
    const __bf16* arow[4];
#pragma unroll
    for (int i = 0; i < 4; ++i) {
        int pos = mt128 + wm + i * 16 + l15;
        if (pos > cntE - 1) pos = cntE - 1;
        arow[i] = X + (size_t)idxl[e * TT + pos] * CC + lq * 8;
    }
    // B staging pointers (2 instrs per matrix per wave)
    const __bf16* gb10 = W1 + (size_t)(n0 + wave * 32 + rl) * CC + c8s;
    const __bf16* gb11 = W1 + (size_t)(n0 + wave * 32 + 16 + rl) * CC + c8s;
    const __bf16* gb30 = W3 + (size_t)(n0 + wave * 32 + rl) * CC + c8s;
    const __bf16* gb31 = W3 + (size_t)(n0 + wave * 32 + 16 + rl) * CC + c8s;
    const int lofs0 = (wave * 32) * 32;
    const int lofs1 = (wave * 32 + 16) * 32;

    f32x4 acc1[4][4] = {};
    f32x4 acc3[4][4] = {};
    bf16x8 aCur[4], aNxt[4];

    auto stageB = [&](int b, int kb) {
        gl_lds16(gb10 + kb, &sB1[b][lofs0]);
        gl_lds16(gb11 + kb, &sB1[b][lofs1]);
        gl_lds16(gb30 + kb, &sB3[b][lofs0]);
        gl_lds16(gb31 + kb, &sB3[b][lofs1]);
    };
    auto loadA = [&](bf16x8* a, int kb) {
#pragma unroll
        for (int i = 0; i < 4; ++i) a[i] = *(const bf16x8*)&arow[i][kb];
    };

    // prologue: stage first (oldest vm ops = the B stage), then A regs
    stageB(0, 0);
    memfence();
    loadA(aCur, 0);
    memfence();

    int p = 0;
    for (int kb = 0; kb < CC; kb += 32, p ^= 1) {
        // my 4 oldest outstanding vm ops are the buf-p stage -> landed
        asm volatile("s_waitcnt vmcnt(4)" ::: "memory");
        barrier_raw();   // everyone's buf-p stage landed; everyone's p^1 reads done

        bf16x8 b1f[4], b3f[4];
#pragma unroll
        for (int j = 0; j < 4; ++j)
            b1f[j] = *(const bf16x8*)&sB1[p][(wn + j * 16 + l15) * 32 + cq];
#pragma unroll
        for (int j = 0; j < 4; ++j)
            b3f[j] = *(const bf16x8*)&sB3[p][(wn + j * 16 + l15) * 32 + cq];

        if (kb + 32 < CC) {
            memfence();
            stageB(p ^ 1, kb + 32);   // issue BEFORE A loads: stage stays oldest
            memfence();
            loadA(aNxt, kb + 32);
            memfence();
        }

        // compiler inserts fine-grained lgkm/vmcnt for b1f/b3f/aCur
#pragma unroll
        for (int i = 0; i < 4; ++i)
#pragma unroll
            for (int j = 0; j < 4; ++j) {
                acc1[i][j] = __builtin_amdgcn_mfma_f32_16x16x32_bf16(
                    aCur[i], b1f[j], acc1[i][j], 0, 0, 0);
                acc3[i][j] = __builtin_amdgcn_mfma_f32_16x16x32_bf16(
                    aCur[i], b3f[j], acc3[i][j], 0, 0, 0);
            }
#pragma unroll
        for (int i = 0; i < 4; ++i) aCur[i] = aNxt[i];
    }

    // epilogue: exact gelu * w3-branch -> packed H rows
#pragma unroll
    for (int i = 0; i < 4; ++i) {
        const int gb = goff + mt128 + wm + i * 16 + lq * 4;
#pragma unroll
        for (int j = 0; j < 4; ++j) {
            const int nb = n0 + wn + j * 16 + l15;
#pragma unroll
            for (int r = 0; r < 4; ++r) {
                const float a  = acc1[i][j][r];
                const float c  = acc3[i][j][r];
                const float ge = 0.5f * a * (1.0f + erff(a * 0.70710678118654752f));
                H[(size_t)(gb + r) * FFN + nb] = (__bf16)(ge * c);
            }
        }
    }
}

// ---------------------------------------------------------------------------
// GEMM2: Z = (H @ W2^T) * posW (combine weight folded in).  Same structure:
// A (H rows) direct-to-register, W2 double-buffered LDS, one barrier/iter.
// grid (C/128, MAXTILES)
// ---------------------------------------------------------------------------
__global__ __launch_bounds__(256, 3)
void k_gemm2(const __bf16* __restrict__ H, const __bf16* __restrict__ w2b,
             const int* __restrict__ off, const int* __restrict__ tileE,
             const int* __restrict__ tileM, const int* __restrict__ nT,
             const float* __restrict__ posW, __bf16* __restrict__ Z) {
    if ((int)blockIdx.y >= nT[0]) return;
    const int e     = tileE[blockIdx.y];
    const int mt128 = tileM[blockIdx.y];
    const int goff  = off[e];
    const int n0    = blockIdx.x * 128;
    const __bf16* W2 = w2b + (size_t)e * CC * FFN;

    __shared__ __bf16 sB[2][128 * 32];

    const int tid  = threadIdx.x;
    const int lane = tid & 63;
    const int wave = tid >> 6;
    const int wm   = (wave & 1) * 64;
    const int wn   = (wave >> 1) * 64;
    const int l15  = lane & 15;
    const int lq   = lane >> 4;
    const int rl   = lane >> 2;
    const int cpos = lane & 3;
    const int c8s = (cpos ^ ((rl >> 1) & 3)) * 8;
    const int cq  = (lq ^ ((l15 >> 1) & 3)) * 8;

    const __bf16* arow[4];
#pragma unroll
    for (int i = 0; i < 4; ++i)
        arow[i] = H + (size_t)(goff + mt128 + wm + i * 16 + l15) * FFN + lq * 8;
    const __bf16* gb0 = W2 + (size_t)(n0 + wave * 32 + rl) * FFN + c8s;
    const __bf16* gb1 = W2 + (size_t)(n0 + wave * 32 + 16 + rl) * FFN + c8s;
    const int lofs0 = (wave * 32) * 32;
    const int lofs1 = (wave * 32 + 16) * 32;

    f32x4 acc[4][4] = {};
    bf16x8 aCur[4], aNxt[4];

    auto stageB = [&](int b, int kb) {
        gl_lds16(gb0 + kb, &sB[b][lofs0]);
        gl_lds16(gb1 + kb, &sB[b][lofs1]);
    };
    auto loadA = [&](bf16x8* a, int kb) {
#pragma unroll
        for (int i = 0; i < 4; ++i) a[i] = *(const bf16x8*)&arow[i][kb];
    };

    stageB(0, 0);
    memfence();
    loadA(aCur, 0);
    memfence();

    int p = 0;
    for (int kb = 0; kb < FFN; kb += 32, p ^= 1) {
        asm volatile("s_waitcnt vmcnt(4)" ::: "memory");   // oldest 2 = stage
        barrier_raw();

        bf16x8 bf[4];
#pragma unroll
        for (int j = 0; j < 4; ++j)
            bf[j] = *(const bf16x8*)&sB[p][(wn + j * 16 + l15) * 32 + cq];

        if (kb + 32 < FFN) {
            memfence();
            stageB(p ^ 1, kb + 32);
            memfence();
            loadA(aNxt, kb + 32);
            memfence();
        }

#pragma unroll
        for (int i = 0; i < 4; ++i)
#pragma unroll
            for (int j = 0; j < 4; ++j)
                acc[i][j] = __builtin_amdgcn_mfma_f32_16x16x32_bf16(
                    aCur[i], bf[j], acc[i][j], 0, 0, 0);
#pragma unroll
        for (int i = 0; i < 4; ++i) aCur[i] = aNxt[i];
    }

    // epilogue: scale by combine weight per packed row, store bf16
#pragma unroll
    for (int i = 0; i < 4; ++i) {
        const int pos = mt128 + wm + i * 16 + lq * 4;   // row within expert
        const int gb  = goff + pos;
        const f32x4 wrow = *(const f32x4*)&posW[e * TT + pos];
#pragma unroll
        for (int j = 0; j < 4; ++j) {
            const int c = n0 + wn + j * 16 + l15;
#pragma unroll
            for (int r = 0; r < 4; ++r)
                Z[(size_t)(gb + r) * CC + c] = (__bf16)(acc[i][j][r] * wrow[r]);
        }
    }
}

// ---------------------------------------------------------------------------
// k_combine: out[t,c] = Z[r1,c] + Z[r2,c] (already weighted), transposed to
// (B,C,H,W).
// ---------------------------------------------------------------------------
__global__ __launch_bounds__(256) void k_combine(const __bf16* __restrict__ Z,
                                                 const int* __restrict__ off,
                                                 const int* __restrict__ tokE,
                                                 const int* __restrict__ tokP,
                                                 float* __restrict__ out) {
    __shared__ float tile[32][33];
    const int t0 = blockIdx.x * 32;
    const int c0 = blockIdx.y * 32;
    const int tx = threadIdx.x & 31;
    const int ty = threadIdx.x >> 5;

#pragma unroll
    for (int i = 0; i < 4; ++i) {
        const int tl = ty + 8 * i;
        const int t  = t0 + tl;
        const int ee = tokE[t];
        const int e1 = ee & 0xff, e2 = ee >> 8;
        const int r1 = off[e1] + tokP[2 * t];
        const int r2 = off[e2] + tokP[2 * t + 1];
        tile[tl][tx] = (float)Z[(size_t)r1 * CC + c0 + tx]
                     + (float)Z[(size_t)r2 * CC + c0 + tx];
    }
    __syncthreads();

    const int b   = t0 >> 12;
    const int hw0 = t0 & 4095;
#pragma unroll
    for (int i = 0; i < 4; ++i) {
        const int cl = ty + 8 * i;
        out[(size_t)b * CC * HWH + (size_t)(c0 + cl) * HWH + hw0 + tx] = tile[tx][cl];
    }
}

// ---------------------------------------------------------------------------
extern "C" void kernel_launch(void* const* d_in, const int* in_sizes, int n_in,
                              void* d_out, int out_size, void* d_ws, size_t ws_size,
                              hipStream_t stream) {
    const float* hs     = (const float*)d_in[0];
    const float* gate_w = (const float*)d_in[1];
    const float* w1     = (const float*)d_in[2];
    const float* w2     = (const float*)d_in[3];
    const float* w3     = (const float*)d_in[4];
    float* out = (float*)d_out;

    const size_t WSZ = (size_t)EE * FFN * CC * 2;   // 16 MB per bf16 weight
    char* ws = (char*)d_ws;
    __bf16* w2b  = (__bf16*)ws;                     // [0, 16M)   live: gemm2
    __bf16* w1b  = (__bf16*)(ws + WSZ);             // [16M,32M)  live: gemm1
    __bf16* w3b  = (__bf16*)(ws + 2 * WSZ);         // [32M,48M)  live: gemm1
    __bf16* X    = (__bf16*)(ws + 3 * WSZ);         // [48M,64M)  live: gemm1
    __bf16* Zbuf = (__bf16*)(ws + WSZ);             // overlays w1b,w3b,X-head
    __bf16* Hbuf = (__bf16*)(ws + 4 * WSZ);         // 34 MB
    float*  logP = (float*)Hbuf;                    // 4 MB, dead before gemm1
    char* p = ws + 4 * WSZ + (size_t)HCAP * FFN * 2;
    int*   idxl  = (int*)p;           p += (size_t)EE * TT * 4;
    int*   tokE  = (int*)p;           p += (size_t)TT * 4;
    int*   tokP  = (int*)p;           p += (size_t)2 * TT * 4;
    float* posW  = (float*)p;         p += (size_t)EE * TT * 4;
    int*   cnt   = (int*)p;           p += 256;
    int*   off   = (int*)p;           p += 256;
    int*   tileE = (int*)p;           p += MAXTILES * 4;
    int*   tileM = (int*)p;           p += MAXTILES * 4;
    int*   nT    = (int*)p;

    hipMemsetAsync(cnt, 0, EE * sizeof(int), stream);

    k_prep<<<CVB + XPB + RTB, 256, 0, stream>>>(
        hs, gate_w, w1, w2, w3, w1b, w2b, w3b, X, logP);
    k_top2<<<TT / 256, 256, 0, stream>>>(logP, cnt, idxl, tokE, tokP, posW);
    k_offsets<<<1, 64, 0, stream>>>(cnt, off, tileE, tileM, nT);

    k_gemm1<<<dim3(FFN / 128, MAXTILES), 256, 0, stream>>>(
        X, w1b, w3b, cnt, off, idxl, tileE, tileM, nT, Hbuf);
    k_gemm2<<<dim3(CC / 128, MAXTILES), 256, 0, stream>>>(
        Hbuf, w2b, off, tileE, tileM, nT, posW, Zbuf);
    k_combine<<<dim3(TT / 32, CC / 32), 256, 0, stream>>>(
        Zbuf, off, tokE, tokP, out);
}